// Round 2
// baseline (498.372 us; speedup 1.0000x reference)
//
#include <hip/hip_runtime.h>
#include <hip/hip_bf16.h>

#define PATCH 4
#define EMBED 96
#define HIN 512
#define WIN 512
#define HP 128
#define WP 128
#define BATCH 8
#define CHAN 8   // 3 rgb + 4 hs + 1 dem

__device__ __forceinline__ float dot4(float4 a, float4 b, float acc) {
    acc = fmaf(a.x, b.x, acc);
    acc = fmaf(a.y, b.y, acc);
    acc = fmaf(a.z, b.z, acc);
    acc = fmaf(a.w, b.w, acc);
    return acc;
}

// Block = 256 threads = one (b, c, hp-octet): 8 hp rows x 128 wp.
// Thread owns 4 consecutive wp's -> float4 stores (1 KB/wave-store).
// W (96x16) + bias staged in LDS once; uniform ds_read_b128 broadcasts.
__global__ __launch_bounds__(256, 2)
void patch_embed_kernel(const float* __restrict__ rgb,
                        const float* __restrict__ hs,
                        const float* __restrict__ dem,
                        const float* __restrict__ W,
                        const float* __restrict__ bias,
                        float* __restrict__ out) {
    __shared__ float sW[EMBED * 16 + EMBED];   // 6528 B

    const int tid = threadIdx.x;
    for (int i = tid; i < EMBED * 16 + EMBED; i += 256) {
        sW[i] = (i < EMBED * 16) ? W[i] : bias[i - EMBED * 16];
    }

    const int blk = blockIdx.x;          // 0 .. 8*8*16-1
    const int hq  = blk & 15;            // hp octet
    const int bc  = blk >> 4;
    const int b   = bc >> 3;
    const int c   = bc & 7;

    const int hp  = hq * 8 + (tid >> 5);     // 8 rows per block, 32 threads/row
    const int wp0 = (tid & 31) * 4;          // 4 wp per thread

    const float* src;
    if (c < 3)      src = rgb + (size_t)(b * 3 + c)       * (HIN * WIN);
    else if (c < 7) src = hs  + (size_t)(b * 4 + (c - 3)) * (HIN * WIN);
    else            src = dem + (size_t)b                 * (HIN * WIN);

    // 4x16 input floats: rows hp*4..hp*4+3, cols wp0*4..wp0*4+15 (64B aligned)
    const float* p = src + (size_t)(hp * PATCH) * WIN + wp0 * PATCH;
    float4 r[4][4];
    #pragma unroll
    for (int dy = 0; dy < 4; ++dy) {
        #pragma unroll
        for (int k = 0; k < 4; ++k) {
            r[dy][k] = *(const float4*)(p + dy * WIN + k * 4);
        }
    }

    __syncthreads();

    float* outp = out + (((size_t)(b * CHAN * EMBED + c * EMBED)) * HP + hp) * WP + wp0;

    #pragma unroll 2
    for (int e = 0; e < EMBED; ++e) {
        const float4* wr = (const float4*)(sW + e * 16);
        const float4 w0 = wr[0], w1 = wr[1], w2 = wr[2], w3 = wr[3];
        const float bb = sW[EMBED * 16 + e];
        float4 o;
        o.x = dot4(r[3][0], w3, dot4(r[2][0], w2, dot4(r[1][0], w1, dot4(r[0][0], w0, bb))));
        o.y = dot4(r[3][1], w3, dot4(r[2][1], w2, dot4(r[1][1], w1, dot4(r[0][1], w0, bb))));
        o.z = dot4(r[3][2], w3, dot4(r[2][2], w2, dot4(r[1][2], w1, dot4(r[0][2], w0, bb))));
        o.w = dot4(r[3][3], w3, dot4(r[2][3], w2, dot4(r[1][3], w1, dot4(r[0][3], w0, bb))));
        *(float4*)(outp + (size_t)e * (HP * WP)) = o;
    }
}

extern "C" void kernel_launch(void* const* d_in, const int* in_sizes, int n_in,
                              void* d_out, int out_size, void* d_ws, size_t ws_size,
                              hipStream_t stream) {
    const float* rgb  = (const float*)d_in[0];
    const float* hs   = (const float*)d_in[1];
    const float* dem  = (const float*)d_in[2];
    const float* W    = (const float*)d_in[3];
    const float* bias = (const float*)d_in[4];
    float* out = (float*)d_out;

    const int grid = BATCH * CHAN * (HP / 8);   // 8*8*16 = 1024 blocks
    patch_embed_kernel<<<grid, 256, 0, stream>>>(rgb, hs, dem, W, bias, out);
}